// Round 11
// baseline (25.695 us; speedup 1.0000x reference)
//
#include <hip/hip_runtime.h>

#define BLOCK 256
#define SEGS  224           // outputs per block; npts <= 224*8 = 1792
#define DN    2976          // staged data floats (covers fallback's 2931)
#define CVP   2112          // padded conv results (j < 2048 unconditional)
#define SG_N  920           // LDS gauss window (fallback only)
#define GTHR  1e-4f
#define NITF  14            // fast-path fixed iteration count (sigma=0.07 -> 14)
#define NL4F  528           // fast-path staged quads (max swz read 526)

// ---------------------------------------------------------------------------
// exact replication of np.linspace element values (float64)
// ---------------------------------------------------------------------------
__device__ __forceinline__ double vnat(int i, double h, int N) {
    if (i == N - 1) return 10501.0;
    return __dadd_rn(__dmul_rn((double)i, h), 9999.0);
}

__device__ __forceinline__ int seg_start(int e, double h, double q, int N) {
    double E = (e >= 500000) ? 10500.0
                             : __dadd_rn(__dmul_rn((double)e, q), 10000.0);
    double g = (E - 9999.0) / h;
    int i = (int)g - 2;
    if (i < 0) i = 0;
    if (i > N) i = N;
    while (i < N && vnat(i, h, N) <= E) ++i;
    while (i > 0 && vnat(i - 1, h, N) > E) --i;
    return i;
}

__device__ __forceinline__ float continuum(int o, const float* __restrict__ wt,
                                           float bias0) {
    double eo  = 10000.0 + (double)o * 0.001;
    double eo1 = 10000.0 + (double)(o + 1) * 0.001;
    double ci  = 0.5 * (eo + eo1);
    double cA  = 0.5 * ((10000.0 + 249999.0 * 0.001) + (10000.0 + 250000.0 * 0.001));
    double cB  = 0.5 * ((10000.0 + 250000.0 * 0.001) + (10000.0 + 250001.0 * 0.001));
    double med = 0.5 * (cA + cB);
    float x = (float)((ci - med) / 20500.0);
    float c = bias0;
    float p = x;
    #pragma unroll
    for (int q = 0; q < 15; ++q) {
        c = fmaf(wt[q], p, c);
        p *= x;
    }
    return c;
}

__device__ __forceinline__ int swz(int p) { return p ^ ((p >> 3) & 1); }

// ---------------------------------------------------------------------------
// Single fused kernel.
// Fast path (nIter<=14): VPT=8 sliding window, XOR-swizzled LDS (1 data
// ds_read_b128 per 32 FMAs), gauss in VGPRs (computed per-lane).
// Fallback: R10's verified two-stream pipelined loop.
// ---------------------------------------------------------------------------
__global__ __launch_bounds__(BLOCK) void fused_kernel(
        const float* __restrict__ a,
        const float* __restrict__ ln_sigma,
        const float* __restrict__ weight,
        const float* __restrict__ bias,
        float* __restrict__ out,
        int N, int M) {
    __shared__ __align__(16) float d[DN];
    __shared__ __align__(16) float sg[SG_N];
    __shared__ float cvp[CVP];
    __shared__ int aseg[256];

    const int t  = threadIdx.x;
    const int b  = blockIdx.x;
    const int o1 = b * SEGS + t;
    const int s0 = b * SEGS + 1;

    const double h = 502.0 / 3999999.0;
    const double q = 500.0 / 500000.0;

    // ---- uniform: gauss params + effective radius ----
    const float sigma  = 0.01f + __expf(ln_sigma[0]);
    const float amp    = 0.01f / (sigma * sqrtf(6.2831853308f));
    const float inv2s2 = 0.5f / (sigma * sigma);
    int r = 450;
    float tg = amp / GTHR;
    if (tg > 1.0f) {
        float xstar = sigma * sqrtf(2.0f * __logf(tg));
        r = (int)(xstar * 100.0f) + 2;
        if (r > 450) r = 450;
    }

    // ---- uniform: block native start + window geometry ----
    const int Bblk  = seg_start(s0 - 1, h, q, N);
    const int gbase = (Bblk - 456) & ~3;
    const int off   = Bblk - 450 - gbase;      // in [6,9]
    int kLo = (450 - r) - ((450 - r + off) & 3);
    const int kHi   = 450 + r;
    const int nIter = (kHi - kLo + 4) >> 2;
    const int i40   = (off + kLo) >> 2;
    const bool fast = (nIter <= NITF);

    float4 G[NITF];

    if (fast) {
        // ---- swizzled staging of quads [i40, i40+NL4F) ----
        const int f0 = gbase + (i40 << 2);     // first staged float
        if (f0 >= 0 && f0 + (NL4F << 2) <= N) {
            const float4* A4 = reinterpret_cast<const float4*>(a) + (f0 >> 2);
            float4* dw = reinterpret_cast<float4*>(d);
            dw[swz(t)]       = A4[t];
            dw[swz(t + 256)] = A4[t + 256];
            if (t < NL4F - 512) dw[swz(t + 512)] = A4[t + 512];
        } else {
            for (int j = t; j < (NL4F << 2); j += BLOCK) {
                int gi = f0 + j;
                float v = (gi >= 0 && gi < N) ? a[gi] : 0.0f;
                d[(swz(j >> 2) << 2) | (j & 3)] = v;
            }
        }
        // ---- gauss quads into VGPRs (hidden under staging latency) ----
        #pragma unroll
        for (int m = 0; m < NITF; ++m) {
            int tap = kLo + 4 * m;             // in [418, 509] subset of [0,900]
            float x0 = (float)((tap     - 450) * 0.01);
            float x1 = (float)((tap + 1 - 450) * 0.01);
            float x2 = (float)((tap + 2 - 450) * 0.01);
            float x3 = (float)((tap + 3 - 450) * 0.01);
            G[m].x = amp * __expf(-x0 * x0 * inv2s2);
            G[m].y = amp * __expf(-x1 * x1 * inv2s2);
            G[m].z = amp * __expf(-x2 * x2 * inv2s2);
            G[m].w = amp * __expf(-x3 * x3 * inv2s2);
        }
    } else {
        // ---- R10 staging (linear) + gauss window into LDS ----
        int NL = off + 2016 + kHi + 6;
        if (NL > DN) NL = DN;
        const int NL4 = (NL + 3) >> 2;
        if (gbase >= 0 && gbase + (NL4 << 2) <= N) {
            const float4* a4 = reinterpret_cast<const float4*>(a) + (gbase >> 2);
            float4* dw = reinterpret_cast<float4*>(d);
            for (int j = t; j < NL4; j += BLOCK) dw[j] = a4[j];
        } else {
            for (int j = t; j < (NL4 << 2); j += BLOCK) {
                int gi = gbase + j;
                d[j] = (gi >= 0 && gi < N) ? a[gi] : 0.0f;
            }
        }
        const int ntap = (nIter << 2) + 8;
        for (int j = t; j < ntap; j += BLOCK) {
            int tap = kLo + j;
            float g = 0.0f;
            if (tap >= 0 && tap <= 900) {
                float x = (float)((tap - 450) * 0.01);
                g = amp * __expf(-x * x * inv2s2);
            }
            sg[j] = g;
        }
    }

    // ---- per-thread segment start (analytic; overlaps staging) ----
    {
        int sc = s0 + t;
        if (sc > 500001) sc = 500001;
        aseg[t] = seg_start(sc - 1, h, q, N);
    }
    __syncthreads();                           // barrier A

    const int A_t  = aseg[t];
    const int A_t1 = (t < 255) ? aseg[t + 1] : A_t;
    const int cnt  = (t < SEGS && o1 < M) ? (A_t1 - A_t) : 0;
    const int excl = A_t - Bblk;

    if (fast) {
        // ---- conv: VPT=8 sliding window, swizzled reads ----
        const float4* dr = reinterpret_cast<const float4*>(d);
        const int p0 = 2 * t;
        float4 W0 = dr[swz(p0)];
        float4 W1 = dr[swz(p0 + 1)];
        float c0=0.f,c1=0.f,c2=0.f,c3=0.f,c4=0.f,c5=0.f,c6=0.f,c7=0.f;
        #pragma unroll
        for (int m = 0; m < NITF; ++m) {
            const float4 W2 = dr[swz(p0 + m + 2)];
            const float4 g  = G[m];
            c0 = fmaf(g.x, W0.x, c0); c0 = fmaf(g.y, W0.y, c0);
            c0 = fmaf(g.z, W0.z, c0); c0 = fmaf(g.w, W0.w, c0);
            c1 = fmaf(g.x, W0.y, c1); c1 = fmaf(g.y, W0.z, c1);
            c1 = fmaf(g.z, W0.w, c1); c1 = fmaf(g.w, W1.x, c1);
            c2 = fmaf(g.x, W0.z, c2); c2 = fmaf(g.y, W0.w, c2);
            c2 = fmaf(g.z, W1.x, c2); c2 = fmaf(g.w, W1.y, c2);
            c3 = fmaf(g.x, W0.w, c3); c3 = fmaf(g.y, W1.x, c3);
            c3 = fmaf(g.z, W1.y, c3); c3 = fmaf(g.w, W1.z, c3);
            c4 = fmaf(g.x, W1.x, c4); c4 = fmaf(g.y, W1.y, c4);
            c4 = fmaf(g.z, W1.z, c4); c4 = fmaf(g.w, W1.w, c4);
            c5 = fmaf(g.x, W1.y, c5); c5 = fmaf(g.y, W1.z, c5);
            c5 = fmaf(g.z, W1.w, c5); c5 = fmaf(g.w, W2.x, c5);
            c6 = fmaf(g.x, W1.z, c6); c6 = fmaf(g.y, W1.w, c6);
            c6 = fmaf(g.z, W2.x, c6); c6 = fmaf(g.w, W2.y, c6);
            c7 = fmaf(g.x, W1.w, c7); c7 = fmaf(g.y, W2.x, c7);
            c7 = fmaf(g.z, W2.y, c7); c7 = fmaf(g.w, W2.z, c7);
            W0 = W1; W1 = W2;
        }
        const int L = 8 * t;
        int j;
        j = L;     cvp[j + (j >> 5)] = c0;
        j = L + 1; cvp[j + (j >> 5)] = c1;
        j = L + 2; cvp[j + (j >> 5)] = c2;
        j = L + 3; cvp[j + (j >> 5)] = c3;
        j = L + 4; cvp[j + (j >> 5)] = c4;
        j = L + 5; cvp[j + (j >> 5)] = c5;
        j = L + 6; cvp[j + (j >> 5)] = c6;
        j = L + 7; cvp[j + (j >> 5)] = c7;
    } else {
        // ---- R10 fallback conv: 2 streams, all-LDS, pipelined ----
        const float4* d4 = reinterpret_cast<const float4*>(d);
        const float4* s4 = reinterpret_cast<const float4*>(sg);
        const int ia = i40 + t, ib = ia + 256;
        float4 vA = d4[ia],     vB = d4[ib];
        float4 nA = d4[ia + 1], nB = d4[ib + 1];
        float4 gq = s4[0];
        float c0=0.f,c1=0.f,c2=0.f,c3=0.f,c4=0.f,c5=0.f,c6=0.f,c7=0.f;
        for (int m = 1; m <= nIter; ++m) {
            const float4 pA = d4[ia + m + 1];
            const float4 pB = d4[ib + m + 1];
            const float4 hq = s4[m];
            c0 = fmaf(gq.x, vA.x, c0); c0 = fmaf(gq.y, vA.y, c0);
            c0 = fmaf(gq.z, vA.z, c0); c0 = fmaf(gq.w, vA.w, c0);
            c1 = fmaf(gq.x, vA.y, c1); c1 = fmaf(gq.y, vA.z, c1);
            c1 = fmaf(gq.z, vA.w, c1); c1 = fmaf(gq.w, nA.x, c1);
            c2 = fmaf(gq.x, vA.z, c2); c2 = fmaf(gq.y, vA.w, c2);
            c2 = fmaf(gq.z, nA.x, c2); c2 = fmaf(gq.w, nA.y, c2);
            c3 = fmaf(gq.x, vA.w, c3); c3 = fmaf(gq.y, nA.x, c3);
            c3 = fmaf(gq.z, nA.y, c3); c3 = fmaf(gq.w, nA.z, c3);
            c4 = fmaf(gq.x, vB.x, c4); c4 = fmaf(gq.y, vB.y, c4);
            c4 = fmaf(gq.z, vB.z, c4); c4 = fmaf(gq.w, vB.w, c4);
            c5 = fmaf(gq.x, vB.y, c5); c5 = fmaf(gq.y, vB.z, c5);
            c5 = fmaf(gq.z, vB.w, c5); c5 = fmaf(gq.w, nB.x, c5);
            c6 = fmaf(gq.x, vB.z, c6); c6 = fmaf(gq.y, vB.w, c6);
            c6 = fmaf(gq.z, nB.x, c6); c6 = fmaf(gq.w, nB.y, c6);
            c7 = fmaf(gq.x, vB.w, c7); c7 = fmaf(gq.y, nB.x, c7);
            c7 = fmaf(gq.z, nB.y, c7); c7 = fmaf(gq.w, nB.z, c7);
            vA = nA; nA = pA; vB = nB; nB = pB; gq = hq;
        }
        const int La = 4 * t, Lb = 1024 + 4 * t;
        int j;
        j = La;     cvp[j + (j >> 5)] = c0;
        j = La + 1; cvp[j + (j >> 5)] = c1;
        j = La + 2; cvp[j + (j >> 5)] = c2;
        j = La + 3; cvp[j + (j >> 5)] = c3;
        j = Lb;     cvp[j + (j >> 5)] = c4;
        j = Lb + 1; cvp[j + (j >> 5)] = c5;
        j = Lb + 2; cvp[j + (j >> 5)] = c6;
        j = Lb + 3; cvp[j + (j >> 5)] = c7;
    }
    __syncthreads();                           // barrier B

    if (t >= SEGS || o1 >= M) return;

    float sum = 0.0f;
    for (int i = 0; i < cnt; ++i) {
        int j = excl + i;
        sum += cvp[j + (j >> 5)];
    }
    float mean = fminf(fmaxf(sum / (float)cnt, 0.0f), 1.0f);
    out[o1] = mean * continuum(o1, weight, bias[0]);
}

// ---------------------------------------------------------------------------
extern "C" void kernel_launch(void* const* d_in, const int* in_sizes, int n_in,
                              void* d_out, int out_size, void* d_ws, size_t ws_size,
                              hipStream_t stream) {
    const float* a      = (const float*)d_in[0];  // high_res_model [4M]
    const float* ln_s   = (const float*)d_in[1];  // ln_sigma [1]
    const float* weight = (const float*)d_in[2];  // [1,15]
    const float* bias   = (const float*)d_in[3];  // [1]
    float* out = (float*)d_out;

    const int N = in_sizes[0];   // 4,000,000
    const int M = out_size;      // 500,000

    const int nb = (M + SEGS - 1) / SEGS;        // 2233
    fused_kernel<<<nb, BLOCK, 0, stream>>>(a, ln_s, weight, bias, out, N, M);
}

// Round 12
// 19.525 us; speedup vs baseline: 1.3160x; 1.3160x over previous
//
#include <hip/hip_runtime.h>

#define BLOCK 256
#define SEGS  224           // outputs per block; npts <= 224*8 = 1792
#define DN    2976          // staged data floats (covers fallback's 2931)
#define CVP   2112          // padded conv results (j < 2048 unconditional)
#define SG_N  920           // LDS gauss window (fallback) / replicas (fast)
#define GTHR  1e-4f
#define NITF  14            // fast-path fixed iteration count
#define NL4F  528           // fast-path staged quads

// ---------------------------------------------------------------------------
// exact replication of np.linspace element values (float64)
// ---------------------------------------------------------------------------
__device__ __forceinline__ double vnat(int i, double h, int N) {
    if (i == N - 1) return 10501.0;
    return __dadd_rn(__dmul_rn((double)i, h), 9999.0);
}

__device__ __forceinline__ int seg_start(int e, double h, double q, int N) {
    double E = (e >= 500000) ? 10500.0
                             : __dadd_rn(__dmul_rn((double)e, q), 10000.0);
    double g = (E - 9999.0) / h;
    int i = (int)g - 2;
    if (i < 0) i = 0;
    if (i > N) i = N;
    while (i < N && vnat(i, h, N) <= E) ++i;
    while (i > 0 && vnat(i - 1, h, N) > E) --i;
    return i;
}

__device__ __forceinline__ float continuum(int o, const float* __restrict__ wt,
                                           float bias0) {
    double eo  = 10000.0 + (double)o * 0.001;
    double eo1 = 10000.0 + (double)(o + 1) * 0.001;
    double ci  = 0.5 * (eo + eo1);
    double cA  = 0.5 * ((10000.0 + 249999.0 * 0.001) + (10000.0 + 250000.0 * 0.001));
    double cB  = 0.5 * ((10000.0 + 250000.0 * 0.001) + (10000.0 + 250001.0 * 0.001));
    double med = 0.5 * (cA + cB);
    float x = (float)((ci - med) / 20500.0);
    float c = bias0;
    float p = x;
    #pragma unroll
    for (int q = 0; q < 15; ++q) {
        c = fmaf(wt[q], p, c);
        p *= x;
    }
    return c;
}

__device__ __forceinline__ int swz(int p) { return p ^ ((p >> 3) & 1); }

// ---------------------------------------------------------------------------
// Single fused kernel.
// Fast path (nIter<=14): VPT=8 sliding window, XOR-swizzled data LDS
// (1 data b128 / 32 FMAs) + bank-staggered gauss replicas (copy t&7).
// Fallback: R10's verified two-stream pipelined loop.
// ---------------------------------------------------------------------------
__global__ __launch_bounds__(BLOCK) void fused_kernel(
        const float* __restrict__ a,
        const float* __restrict__ ln_sigma,
        const float* __restrict__ weight,
        const float* __restrict__ bias,
        float* __restrict__ out,
        int N, int M) {
    __shared__ __align__(16) float d[DN];
    __shared__ __align__(16) float sg[SG_N];
    __shared__ float cvp[CVP];
    __shared__ int aseg[256];

    const int t  = threadIdx.x;
    const int b  = blockIdx.x;
    const int o1 = b * SEGS + t;
    const int s0 = b * SEGS + 1;

    const double h = 502.0 / 3999999.0;
    const double q = 500.0 / 500000.0;

    // ---- uniform: gauss params + effective radius ----
    const float sigma  = 0.01f + __expf(ln_sigma[0]);
    const float amp    = 0.01f / (sigma * sqrtf(6.2831853308f));
    const float inv2s2 = 0.5f / (sigma * sigma);
    int r = 450;
    float tg = amp / GTHR;
    if (tg > 1.0f) {
        float xstar = sigma * sqrtf(2.0f * __logf(tg));
        r = (int)(xstar * 100.0f) + 2;
        if (r > 450) r = 450;
    }

    // ---- uniform: block native start + window geometry ----
    const int Bblk  = seg_start(s0 - 1, h, q, N);
    const int gbase = (Bblk - 456) & ~3;
    const int off   = Bblk - 450 - gbase;      // in [6,9]
    int kLo = (450 - r) - ((450 - r + off) & 3);
    const int kHi   = 450 + r;
    const int nIter = (kHi - kLo + 4) >> 2;
    const int i40   = (off + kLo) >> 2;
    const bool fast = (nIter <= NITF);

    if (fast) {
        // ---- swizzled staging of quads [i40, i40+NL4F) ----
        const int f0 = gbase + (i40 << 2);
        if (f0 >= 0 && f0 + (NL4F << 2) <= N) {
            const float4* A4 = reinterpret_cast<const float4*>(a) + (f0 >> 2);
            float4* dw = reinterpret_cast<float4*>(d);
            dw[swz(t)]       = A4[t];
            dw[swz(t + 256)] = A4[t + 256];
            if (t < NL4F - 512) dw[swz(t + 512)] = A4[t + 512];
        } else {
            for (int j = t; j < (NL4F << 2); j += BLOCK) {
                int gi = f0 + j;
                float v = (gi >= 0 && gi < N) ? a[gi] : 0.0f;
                d[(swz(j >> 2) << 2) | (j & 3)] = v;
            }
        }
        // ---- 8 bank-staggered gauss replicas: copy k at float 68k ----
        for (int j = t; j < 512; j += BLOCK) {     // 2 iterations
            const int k = j >> 6, i = j & 63;
            const int tap = kLo + i;
            float g = 0.0f;
            if (tap >= 0 && tap <= 900) {
                float x = (float)((tap - 450) * 0.01);
                g = amp * __expf(-x * x * inv2s2);
            }
            sg[68 * k + i] = g;
        }
    } else {
        // ---- R10 staging (linear) + gauss window into LDS ----
        int NL = off + 2016 + kHi + 6;
        if (NL > DN) NL = DN;
        const int NL4 = (NL + 3) >> 2;
        if (gbase >= 0 && gbase + (NL4 << 2) <= N) {
            const float4* a4 = reinterpret_cast<const float4*>(a) + (gbase >> 2);
            float4* dw = reinterpret_cast<float4*>(d);
            for (int j = t; j < NL4; j += BLOCK) dw[j] = a4[j];
        } else {
            for (int j = t; j < (NL4 << 2); j += BLOCK) {
                int gi = gbase + j;
                d[j] = (gi >= 0 && gi < N) ? a[gi] : 0.0f;
            }
        }
        const int ntap = (nIter << 2) + 8;
        for (int j = t; j < ntap; j += BLOCK) {
            int tap = kLo + j;
            float g = 0.0f;
            if (tap >= 0 && tap <= 900) {
                float x = (float)((tap - 450) * 0.01);
                g = amp * __expf(-x * x * inv2s2);
            }
            sg[j] = g;
        }
    }

    // ---- per-thread segment start (analytic; overlaps staging) ----
    {
        int sc = s0 + t;
        if (sc > 500001) sc = 500001;
        aseg[t] = seg_start(sc - 1, h, q, N);
    }
    __syncthreads();                           // barrier A

    const int A_t  = aseg[t];
    const int A_t1 = (t < 255) ? aseg[t + 1] : A_t;
    const int cnt  = (t < SEGS && o1 < M) ? (A_t1 - A_t) : 0;
    const int excl = A_t - Bblk;

    if (fast) {
        // ---- conv: VPT=8 sliding window; 1 data + 1 replica b128 / iter ----
        const float4* dr = reinterpret_cast<const float4*>(d);
        const float4* gr = reinterpret_cast<const float4*>(sg) + 17 * (t & 7);
        const int p0 = 2 * t;
        float4 W0 = dr[swz(p0)];
        float4 W1 = dr[swz(p0 + 1)];
        float c0=0.f,c1=0.f,c2=0.f,c3=0.f,c4=0.f,c5=0.f,c6=0.f,c7=0.f;
        #pragma unroll
        for (int m = 0; m < NITF; ++m) {
            const float4 W2 = dr[swz(p0 + m + 2)];
            const float4 g  = gr[m];
            c0 = fmaf(g.x, W0.x, c0); c0 = fmaf(g.y, W0.y, c0);
            c0 = fmaf(g.z, W0.z, c0); c0 = fmaf(g.w, W0.w, c0);
            c1 = fmaf(g.x, W0.y, c1); c1 = fmaf(g.y, W0.z, c1);
            c1 = fmaf(g.z, W0.w, c1); c1 = fmaf(g.w, W1.x, c1);
            c2 = fmaf(g.x, W0.z, c2); c2 = fmaf(g.y, W0.w, c2);
            c2 = fmaf(g.z, W1.x, c2); c2 = fmaf(g.w, W1.y, c2);
            c3 = fmaf(g.x, W0.w, c3); c3 = fmaf(g.y, W1.x, c3);
            c3 = fmaf(g.z, W1.y, c3); c3 = fmaf(g.w, W1.z, c3);
            c4 = fmaf(g.x, W1.x, c4); c4 = fmaf(g.y, W1.y, c4);
            c4 = fmaf(g.z, W1.z, c4); c4 = fmaf(g.w, W1.w, c4);
            c5 = fmaf(g.x, W1.y, c5); c5 = fmaf(g.y, W1.z, c5);
            c5 = fmaf(g.z, W1.w, c5); c5 = fmaf(g.w, W2.x, c5);
            c6 = fmaf(g.x, W1.z, c6); c6 = fmaf(g.y, W1.w, c6);
            c6 = fmaf(g.z, W2.x, c6); c6 = fmaf(g.w, W2.y, c6);
            c7 = fmaf(g.x, W1.w, c7); c7 = fmaf(g.y, W2.x, c7);
            c7 = fmaf(g.z, W2.y, c7); c7 = fmaf(g.w, W2.z, c7);
            W0 = W1; W1 = W2;
        }
        const int L = 8 * t;
        int j;
        j = L;     cvp[j + (j >> 5)] = c0;
        j = L + 1; cvp[j + (j >> 5)] = c1;
        j = L + 2; cvp[j + (j >> 5)] = c2;
        j = L + 3; cvp[j + (j >> 5)] = c3;
        j = L + 4; cvp[j + (j >> 5)] = c4;
        j = L + 5; cvp[j + (j >> 5)] = c5;
        j = L + 6; cvp[j + (j >> 5)] = c6;
        j = L + 7; cvp[j + (j >> 5)] = c7;
    } else {
        // ---- R10 fallback conv: 2 streams, all-LDS, pipelined ----
        const float4* d4 = reinterpret_cast<const float4*>(d);
        const float4* s4 = reinterpret_cast<const float4*>(sg);
        const int ia = i40 + t, ib = ia + 256;
        float4 vA = d4[ia],     vB = d4[ib];
        float4 nA = d4[ia + 1], nB = d4[ib + 1];
        float4 gq = s4[0];
        float c0=0.f,c1=0.f,c2=0.f,c3=0.f,c4=0.f,c5=0.f,c6=0.f,c7=0.f;
        for (int m = 1; m <= nIter; ++m) {
            const float4 pA = d4[ia + m + 1];
            const float4 pB = d4[ib + m + 1];
            const float4 hq = s4[m];
            c0 = fmaf(gq.x, vA.x, c0); c0 = fmaf(gq.y, vA.y, c0);
            c0 = fmaf(gq.z, vA.z, c0); c0 = fmaf(gq.w, vA.w, c0);
            c1 = fmaf(gq.x, vA.y, c1); c1 = fmaf(gq.y, vA.z, c1);
            c1 = fmaf(gq.z, vA.w, c1); c1 = fmaf(gq.w, nA.x, c1);
            c2 = fmaf(gq.x, vA.z, c2); c2 = fmaf(gq.y, vA.w, c2);
            c2 = fmaf(gq.z, nA.x, c2); c2 = fmaf(gq.w, nA.y, c2);
            c3 = fmaf(gq.x, vA.w, c3); c3 = fmaf(gq.y, nA.x, c3);
            c3 = fmaf(gq.z, nA.y, c3); c3 = fmaf(gq.w, nA.z, c3);
            c4 = fmaf(gq.x, vB.x, c4); c4 = fmaf(gq.y, vB.y, c4);
            c4 = fmaf(gq.z, vB.z, c4); c4 = fmaf(gq.w, vB.w, c4);
            c5 = fmaf(gq.x, vB.y, c5); c5 = fmaf(gq.y, vB.z, c5);
            c5 = fmaf(gq.z, vB.w, c5); c5 = fmaf(gq.w, nB.x, c5);
            c6 = fmaf(gq.x, vB.z, c6); c6 = fmaf(gq.y, vB.w, c6);
            c6 = fmaf(gq.z, nB.x, c6); c6 = fmaf(gq.w, nB.y, c6);
            c7 = fmaf(gq.x, vB.w, c7); c7 = fmaf(gq.y, nB.x, c7);
            c7 = fmaf(gq.z, nB.y, c7); c7 = fmaf(gq.w, nB.z, c7);
            vA = nA; nA = pA; vB = nB; nB = pB; gq = hq;
        }
        const int La = 4 * t, Lb = 1024 + 4 * t;
        int j;
        j = La;     cvp[j + (j >> 5)] = c0;
        j = La + 1; cvp[j + (j >> 5)] = c1;
        j = La + 2; cvp[j + (j >> 5)] = c2;
        j = La + 3; cvp[j + (j >> 5)] = c3;
        j = Lb;     cvp[j + (j >> 5)] = c4;
        j = Lb + 1; cvp[j + (j >> 5)] = c5;
        j = Lb + 2; cvp[j + (j >> 5)] = c6;
        j = Lb + 3; cvp[j + (j >> 5)] = c7;
    }
    __syncthreads();                           // barrier B

    if (t >= SEGS || o1 >= M) return;

    float sum = 0.0f;
    for (int i = 0; i < cnt; ++i) {
        int j = excl + i;
        sum += cvp[j + (j >> 5)];
    }
    float mean = fminf(fmaxf(sum / (float)cnt, 0.0f), 1.0f);
    out[o1] = mean * continuum(o1, weight, bias[0]);
}

// ---------------------------------------------------------------------------
extern "C" void kernel_launch(void* const* d_in, const int* in_sizes, int n_in,
                              void* d_out, int out_size, void* d_ws, size_t ws_size,
                              hipStream_t stream) {
    const float* a      = (const float*)d_in[0];  // high_res_model [4M]
    const float* ln_s   = (const float*)d_in[1];  // ln_sigma [1]
    const float* weight = (const float*)d_in[2];  // [1,15]
    const float* bias   = (const float*)d_in[3];  // [1]
    float* out = (float*)d_out;

    const int N = in_sizes[0];   // 4,000,000
    const int M = out_size;      // 500,000

    const int nb = (M + SEGS - 1) / SEGS;        // 2233
    fused_kernel<<<nb, BLOCK, 0, stream>>>(a, ln_s, weight, bias, out, N, M);
}

// Round 13
// 18.389 us; speedup vs baseline: 1.3973x; 1.0618x over previous
//
#include <hip/hip_runtime.h>

#define BLOCK 256
#define SEGS  224           // outputs per block; npts <= 224*8 = 1792
#define GTHR  1e-4f
#define NITF  14            // fast-path fixed iteration count (r <= 26)
#define NQ    534           // fast-path staged quads (max read idx 531)
// pool layout (floats)
#define SG_F   2136         // gauss replicas (544) | fallback gauss window at 0
#define CVP_F  2688         // padded conv results (2112)
#define ASEG_F 4800         // int[256]
#define POOL_F 5056         // 20224 B -> 8 blocks/CU

// ---------------------------------------------------------------------------
// exact replication of np.linspace element values (float64); div-free seed
// ---------------------------------------------------------------------------
__device__ __forceinline__ double vnat(int i, double h, int N) {
    if (i == N - 1) return 10501.0;
    return __dadd_rn(__dmul_rn((double)i, h), 9999.0);
}

__device__ __forceinline__ int seg_start(int e, double h, double inv_h, int N) {
    double E = (e >= 500000) ? 10500.0
                             : __dadd_rn(__dmul_rn((double)e, 0.001), 10000.0);
    double g = __dmul_rn(E - 9999.0, inv_h);
    int i = (int)g - 2;
    if (i < 0) i = 0;
    if (i > N) i = N;
    while (i < N && vnat(i, h, N) <= E) ++i;      // exact upward fixup
    while (i > 0 && vnat(i - 1, h, N) > E) --i;   // exact downward fixup
    return i;
}

__device__ __forceinline__ float continuum(int o, const float* __restrict__ wt,
                                           float bias0) {
    double eo  = 10000.0 + (double)o * 0.001;
    double eo1 = 10000.0 + (double)(o + 1) * 0.001;
    double ci  = 0.5 * (eo + eo1);
    double cA  = 0.5 * ((10000.0 + 249999.0 * 0.001) + (10000.0 + 250000.0 * 0.001));
    double cB  = 0.5 * ((10000.0 + 250000.0 * 0.001) + (10000.0 + 250001.0 * 0.001));
    double med = 0.5 * (cA + cB);
    float x = (float)((ci - med) * (1.0 / 20500.0));
    float c = bias0;
    float p = x;
    #pragma unroll
    for (int q = 0; q < 15; ++q) {
        c = fmaf(wt[q], p, c);
        p *= x;
    }
    return c;
}

__device__ __forceinline__ int swz(int p) { return p ^ ((p >> 3) & 1); }

// ---------------------------------------------------------------------------
// Single fused kernel, 20 KB LDS pool (8 blocks/CU), stage-first prologue.
// Fast path (r<=26): VPT=8 sliding window, XOR-swizzled data, bank-staggered
// gauss replicas. Fallback (cold): global-read conv, correctness only.
// ---------------------------------------------------------------------------
__global__ __launch_bounds__(BLOCK, 8) void fused_kernel(
        const float* __restrict__ a,
        const float* __restrict__ ln_sigma,
        const float* __restrict__ weight,
        const float* __restrict__ bias,
        float* __restrict__ out,
        int N, int M) {
    __shared__ __align__(16) float pool[POOL_F];
    float* dd   = pool;                 // fast: staged data (2136 floats)
    float* sgf  = pool + SG_F;          // fast: 8 gauss replicas (544)
    float* sgs  = pool;                 // fallback: gauss window (<=920)
    float* cvp  = pool + CVP_F;         // both: padded conv results (2112)
    int*   aseg = (int*)(pool + ASEG_F);

    const int t  = threadIdx.x;
    const int b  = blockIdx.x;
    const int o1 = b * SEGS + t;
    const int s0 = b * SEGS + 1;

    const double h     = 502.0 / 3999999.0;
    const double inv_h = 3999999.0 / 502.0;

    // ---- uniform: gauss params + effective radius (cheap, fp32) ----
    const float sigma  = 0.01f + __expf(ln_sigma[0]);
    const float amp    = 0.01f / (sigma * sqrtf(6.2831853308f));
    const float inv2s2 = 0.5f / (sigma * sigma);
    int r = 450;
    float tg = amp / GTHR;
    if (tg > 1.0f) {
        float xstar = sigma * sqrtf(2.0f * __logf(tg));
        r = (int)(xstar * 100.0f) + 2;
        if (r > 450) r = 450;
    }
    const bool fast = (r <= 26);       // => nIter <= 14 for any alignment

    // ---- approx stage origin from one f64 multiply (error <= ~2) ----
    const int e0 = b * SEGS;           // = s0 - 1, always < 500000
    const double E0   = __dadd_rn(__dmul_rn((double)e0, 0.001), 10000.0);
    const double iest = __dmul_rn(E0 - 9999.0, inv_h);
    const int st0 = (((int)iest) - r - 16) & ~3;

    if (fast) {
        // ---- STAGE FIRST: swizzled quads [st0, st0 + 4*NQ) ----
        if (st0 >= 0 && st0 + (NQ << 2) <= N) {
            const float4* A4 = reinterpret_cast<const float4*>(a) + (st0 >> 2);
            float4* dw = reinterpret_cast<float4*>(dd);
            dw[swz(t)]       = A4[t];
            dw[swz(t + 256)] = A4[t + 256];
            if (t < NQ - 512) dw[swz(t + 512)] = A4[t + 512];
        } else {
            for (int j = t; j < (NQ << 2); j += BLOCK) {
                int gi = st0 + j;
                float v = (gi >= 0 && gi < N) ? a[gi] : 0.0f;
                dd[(swz(j >> 2) << 2) | (j & 3)] = v;
            }
        }
    }

    // ---- exact geometry (f64, overlaps staging latency) ----
    const int Bblk = seg_start(e0, h, inv_h, N);
    const int off2 = Bblk - 450 - st0;
    int kLo = (450 - r) - ((450 - r + off2) & 3);  // (off2+kLo) % 4 == 0
    const int kHi   = 450 + r;
    const int nIter = (kHi - kLo + 4) >> 2;
    const int i40   = (off2 + kLo) >> 2;           // in [2, 6]

    if (fast) {
        // ---- 8 bank-staggered gauss replicas: copy k at float 68k ----
        for (int j = t; j < 512; j += BLOCK) {     // 2 iterations
            const int k = j >> 6, i = j & 63;
            const int tap = kLo + i;               // in [418, 545] ⊂ [0,900]
            float x = (float)((tap - 450) * 0.01);
            sgf[68 * k + i] = amp * __expf(-x * x * inv2s2);
        }
    } else {
        // ---- fallback: gauss window at pool[0..] ----
        const int ntap = (nIter << 2) + 8;
        for (int j = t; j < ntap; j += BLOCK) {
            int tap = kLo + j;
            float g = 0.0f;
            if (tap >= 0 && tap <= 900) {
                float x = (float)((tap - 450) * 0.01);
                g = amp * __expf(-x * x * inv2s2);
            }
            sgs[j] = g;
        }
    }

    // ---- per-thread segment start (exact, overlaps staging) ----
    {
        int sc = s0 + t;
        if (sc > 500001) sc = 500001;
        aseg[t] = seg_start(sc - 1, h, inv_h, N);
    }
    __syncthreads();                               // barrier A

    const int A_t  = aseg[t];
    const int A_t1 = (t < 255) ? aseg[t + 1] : A_t;
    const int cnt  = (t < SEGS && o1 < M) ? (A_t1 - A_t) : 0;
    const int excl = A_t - Bblk;

    if (fast) {
        // ---- conv: VPT=8 sliding window; 1 data + 1 gauss b128 / iter ----
        const float4* dr = reinterpret_cast<const float4*>(dd);
        const float4* gr = reinterpret_cast<const float4*>(sgf) + 17 * (t & 7);
        const int p0 = i40 + 2 * t;
        float4 W0 = dr[swz(p0)];
        float4 W1 = dr[swz(p0 + 1)];
        float c0=0.f,c1=0.f,c2=0.f,c3=0.f,c4=0.f,c5=0.f,c6=0.f,c7=0.f;
        #pragma unroll
        for (int m = 0; m < NITF; ++m) {
            const float4 W2 = dr[swz(p0 + m + 2)];
            const float4 g  = gr[m];
            c0 = fmaf(g.x, W0.x, c0); c0 = fmaf(g.y, W0.y, c0);
            c0 = fmaf(g.z, W0.z, c0); c0 = fmaf(g.w, W0.w, c0);
            c1 = fmaf(g.x, W0.y, c1); c1 = fmaf(g.y, W0.z, c1);
            c1 = fmaf(g.z, W0.w, c1); c1 = fmaf(g.w, W1.x, c1);
            c2 = fmaf(g.x, W0.z, c2); c2 = fmaf(g.y, W0.w, c2);
            c2 = fmaf(g.z, W1.x, c2); c2 = fmaf(g.w, W1.y, c2);
            c3 = fmaf(g.x, W0.w, c3); c3 = fmaf(g.y, W1.x, c3);
            c3 = fmaf(g.z, W1.y, c3); c3 = fmaf(g.w, W1.z, c3);
            c4 = fmaf(g.x, W1.x, c4); c4 = fmaf(g.y, W1.y, c4);
            c4 = fmaf(g.z, W1.z, c4); c4 = fmaf(g.w, W1.w, c4);
            c5 = fmaf(g.x, W1.y, c5); c5 = fmaf(g.y, W1.z, c5);
            c5 = fmaf(g.z, W1.w, c5); c5 = fmaf(g.w, W2.x, c5);
            c6 = fmaf(g.x, W1.z, c6); c6 = fmaf(g.y, W1.w, c6);
            c6 = fmaf(g.z, W2.x, c6); c6 = fmaf(g.w, W2.y, c6);
            c7 = fmaf(g.x, W1.w, c7); c7 = fmaf(g.y, W2.x, c7);
            c7 = fmaf(g.z, W2.y, c7); c7 = fmaf(g.w, W2.z, c7);
            W0 = W1; W1 = W2;
        }
        const int L = 8 * t;
        int j;
        j = L;     cvp[j + (j >> 5)] = c0;
        j = L + 1; cvp[j + (j >> 5)] = c1;
        j = L + 2; cvp[j + (j >> 5)] = c2;
        j = L + 3; cvp[j + (j >> 5)] = c3;
        j = L + 4; cvp[j + (j >> 5)] = c4;
        j = L + 5; cvp[j + (j >> 5)] = c5;
        j = L + 6; cvp[j + (j >> 5)] = c6;
        j = L + 7; cvp[j + (j >> 5)] = c7;
    } else {
        // ---- fallback conv: global reads (cold correctness path) ----
        #pragma unroll 1
        for (int u = 0; u < 8; ++u) {
            const int p = Bblk + 8 * t + u;
            float s = 0.0f;
            for (int k = kLo; k <= kHi; ++k) {
                const int gi = p + k - 450;
                const float av = (gi >= 0 && gi < N) ? a[gi] : 0.0f;
                s = fmaf(av, sgs[k - kLo], s);
            }
            const int j = 8 * t + u;
            cvp[j + (j >> 5)] = s;
        }
    }
    __syncthreads();                               // barrier B

    if (t >= SEGS || o1 >= M) return;

    float sum = 0.0f;
    for (int i = 0; i < cnt; ++i) {
        int j = excl + i;
        sum += cvp[j + (j >> 5)];
    }
    float mean = fminf(fmaxf(sum / (float)cnt, 0.0f), 1.0f);
    out[o1] = mean * continuum(o1, weight, bias[0]);
}

// ---------------------------------------------------------------------------
extern "C" void kernel_launch(void* const* d_in, const int* in_sizes, int n_in,
                              void* d_out, int out_size, void* d_ws, size_t ws_size,
                              hipStream_t stream) {
    const float* a      = (const float*)d_in[0];  // high_res_model [4M]
    const float* ln_s   = (const float*)d_in[1];  // ln_sigma [1]
    const float* weight = (const float*)d_in[2];  // [1,15]
    const float* bias   = (const float*)d_in[3];  // [1]
    float* out = (float*)d_out;

    const int N = in_sizes[0];   // 4,000,000
    const int M = out_size;      // 500,000

    const int nb = (M + SEGS - 1) / SEGS;        // 2233
    fused_kernel<<<nb, BLOCK, 0, stream>>>(a, ln_s, weight, bias, out, N, M);
}